// Round 7
// baseline (133.281 us; speedup 1.0000x reference)
//
#include <hip/hip_runtime.h>
#include <math.h>

// VQ-VAE vector quantizer for MI355X (gfx950).
// z: [32768, 64] fp32, codebook: [1024, 64] fp32.
// Outputs (flat float32, concatenated): quantized_st [32768*64], vq_loss [1],
// indices [32768] (as float), perplexity [1].
//
// R17: R16's direct counters: vq_main 50us, Mfma 9.6%, VALU 29%, HBM 3.9%,
// L2-resident inputs -> ~85% stall, latency/barrier-bound. Mechanism (m97):
// compiler emits s_waitcnt vmcnt(0) lgkmcnt(0) before EVERY s_barrier; our
// loop barriers each phase right after issuing stage loads -> full load
// latency on every phase's critical path at 2 waves/SIMD. All in-barrier
// levers (prefetch depth R15, occupancy R13, phases R12) null by construction.
// R17 removes the barriers: B-fragments gathered DIRECTLY global->reg from
// L2-resident bsplit (slot ((i*4+quad)*BCH+col) == bsplit[(kb+col)*128 +
// (i*4+quad)*8]), one-tile-ahead prefetch in named reg sets, ZERO
// __syncthreads in the K-loop (only counted vmcnt before use). Cost: 4x L2
// reads of bsplit (512MB @ ~35TB/s ~= 15us, overlapped). Fold/butterfly/
// recheck/epilogue/vq_final revert to R13 verbatim (all R16 tweaks dropped).
// Numerics: 3-term split-bf16 + exact fp32 recheck (margin 1e-5), unchanged.

#define D 64
#define KC 1024
#define ROWS 64           // rows per block (4 waves x 16 rows)
#define TC 32             // codes per tile
#define NT (KC / TC)      // 32 tiles

typedef short short8 __attribute__((ext_vector_type(8)));
typedef short short4v __attribute__((ext_vector_type(4)));
typedef float f32x4 __attribute__((ext_vector_type(4)));

__device__ __forceinline__ unsigned short f2bf(float x) {
  unsigned int u = __float_as_uint(x);
  unsigned int r = (u + 0x7fffu + ((u >> 16) & 1u)) >> 16;
  return (unsigned short)r;
}
__device__ __forceinline__ float bf2f(unsigned short h) {
  return __uint_as_float((unsigned int)h << 16);
}

// split two float4 (8 floats) into hi/lo bf16 short8
__device__ __forceinline__ void split8(const float4 a, const float4 b,
                                       short8* hi, short8* lo) {
  float f[8] = {a.x, a.y, a.z, a.w, b.x, b.y, b.z, b.w};
#pragma unroll
  for (int i = 0; i < 8; ++i) {
    unsigned short h = f2bf(f[i]);
    (*hi)[i] = (short)h;
    (*lo)[i] = (short)f2bf(f[i] - bf2f(h));
  }
}

// Precompute: exact fp32 code norms, split-bf16 codebook
// bsplit[k][128] = [e_hi(64) | e_lo(64)], zero hist/loss.
__global__ __launch_bounds__(256) void vq_prep(
    const float* __restrict__ cb, unsigned short* __restrict__ bsplit,
    float* __restrict__ cbn, unsigned int* __restrict__ hist,
    float* __restrict__ loss_acc) {
  const int k = blockIdx.x * 256 + threadIdx.x;  // 0..1023
  const float4* e = (const float4*)(cb + (size_t)k * D);
  unsigned short* bp = bsplit + (size_t)k * 128;
  float s0 = 0.f, s1 = 0.f, s2 = 0.f, s3 = 0.f;
#pragma unroll
  for (int i = 0; i < 16; ++i) {
    float4 v = e[i];
    s0 = fmaf(v.x, v.x, s0);
    s1 = fmaf(v.y, v.y, s1);
    s2 = fmaf(v.z, v.z, s2);
    s3 = fmaf(v.w, v.w, s3);
    unsigned short h0 = f2bf(v.x), h1 = f2bf(v.y), h2 = f2bf(v.z), h3 = f2bf(v.w);
    short4v hv = {(short)h0, (short)h1, (short)h2, (short)h3};
    short4v lv = {(short)f2bf(v.x - bf2f(h0)), (short)f2bf(v.y - bf2f(h1)),
                  (short)f2bf(v.z - bf2f(h2)), (short)f2bf(v.w - bf2f(h3))};
    *(short4v*)(bp + i * 4) = hv;
    *(short4v*)(bp + 64 + i * 4) = lv;
  }
  cbn[k] = (s0 + s1) + (s2 + s3);
  hist[k] = 0u;
  if (k == 0) loss_acc[0] = 0.f;
}

__global__ __launch_bounds__(256, 2) void vq_main(
    const float* __restrict__ z, const unsigned short* __restrict__ bsplit,
    const float* __restrict__ cbn, const float* __restrict__ cb,
    float* __restrict__ out_q, float* __restrict__ out_idx,
    unsigned int* __restrict__ hist, float* __restrict__ loss_acc) {
  __shared__ float scbn[KC];
  __shared__ int skf[ROWS];
  __shared__ float swav[4];
  __shared__ unsigned int lhist[KC];

  const int tid = threadIdx.x;
  const int lane = tid & 63;
  const int wav = tid >> 6;
  const int quad = lane >> 4;
  const int col = lane & 15;
  const int rowbase = blockIdx.x * ROWS;

  // ---- prologue
  // Direct A-fragment z loads: lane owns row wav*16+col,
  // k in {quad*8..+8, 32+quad*8..+8} -> 4 float4 (issue first, longest dep).
  const int arow = rowbase + wav * 16 + col;
  const float4* zr = (const float4*)(z + (size_t)arow * D);
  const float4 f0 = zr[quad * 2];
  const float4 f1 = zr[quad * 2 + 1];
  const float4 f2 = zr[8 + quad * 2];
  const float4 f3 = zr[8 + quad * 2 + 1];

  // cbn -> LDS, zero lhist
  *(float4*)&scbn[tid * 4] = *(const float4*)&cbn[tid * 4];
#pragma unroll
  for (int j = 0; j < KC / 256; ++j) lhist[tid + 256 * j] = 0u;

  // Per-lane B-fragment gather bases (global, L2-resident bsplit).
  // Chain A = code kb+col, chain B = code kb+col+16; frag i at plane-chunk
  // i*4+quad: addr (shorts) = (kb+col)*128 + i*32 + quad*8.
  const unsigned short* pbA = bsplit + (size_t)col * 128 + quad * 8;
  const unsigned short* pbB = pbA + 16 * 128;

  // in-register split-bf16 A-frags
  short8 a0, a1, a2, a3;
  split8(f0, f1, &a0, &a2);  // z_hi / z_lo, k = quad*8 .. +8
  split8(f2, f3, &a1, &a3);  // z_hi / z_lo, k = 32+quad*8 .. +8

  // row norm: per-lane partial (16 elems), quads of same col cover the row.
  float nrm = ((f0.x * f0.x + f0.y * f0.y) + (f0.z * f0.z + f0.w * f0.w)) +
              ((f1.x * f1.x + f1.y * f1.y) + (f1.z * f1.z + f1.w * f1.w)) +
              ((f2.x * f2.x + f2.y * f2.y) + (f2.z * f2.z + f2.w * f2.w)) +
              ((f3.x * f3.x + f3.y * f3.y) + (f3.z * f3.z + f3.w * f3.w));
  nrm += __shfl_xor(nrm, 16, 64);
  nrm += __shfl_xor(nrm, 32, 64);
  // Norm is row-constant so it cancels in all same-row comparisons.
  float rzv[4];
#pragma unroll
  for (int r = 0; r < 4; ++r) rzv[r] = __shfl(nrm, quad * 4 + r, 64);

  __syncthreads();  // scbn + lhist ready; the ONLY block barrier before tail

  // per-lane exact top-2 over this lane's code class (col mod 16)
  float b1d[4], b2d[4];
  int b1k[4], b2k[4];
#pragma unroll
  for (int i = 0; i < 4; ++i) {
    b1d[i] = 3.4e38f; b2d[i] = 3.4e38f;
    b1k[i] = 0x7fffffff; b2k[i] = 0x7fffffff;
  }

  // gather one tile's 8 B-fragments (global -> regs)
  auto load_tile = [&](int kb, short8& bA0, short8& bA1, short8& bA2,
                       short8& bA3, short8& bB0, short8& bB1, short8& bB2,
                       short8& bB3) {
    const unsigned short* pA = pbA + (size_t)kb * 128;
    const unsigned short* pB = pbB + (size_t)kb * 128;
    bA0 = *(const short8*)(pA + 0);
    bA1 = *(const short8*)(pA + 32);
    bA2 = *(const short8*)(pA + 64);
    bA3 = *(const short8*)(pA + 96);
    bB0 = *(const short8*)(pB + 0);
    bB1 = *(const short8*)(pB + 32);
    bB2 = *(const short8*)(pB + 64);
    bB3 = *(const short8*)(pB + 96);
  };

  // compute one tile (R13 MFMA pattern + fold, verbatim semantics)
  auto compute_tile = [&](int kb, const short8 bA0, const short8 bA1,
                          const short8 bA2, const short8 bA3, const short8 bB0,
                          const short8 bB1, const short8 bB2,
                          const short8 bB3) {
    const float enA = scbn[kb + col];
    const float enB = scbn[kb + 16 + col];
    f32x4 accA = {0.f, 0.f, 0.f, 0.f}, accB = {0.f, 0.f, 0.f, 0.f};
    // 3-term split: hi.hi + lo.hi + hi.lo ; two independent chains
    accA = __builtin_amdgcn_mfma_f32_16x16x32_bf16(a0, bA0, accA, 0, 0, 0);
    accB = __builtin_amdgcn_mfma_f32_16x16x32_bf16(a0, bB0, accB, 0, 0, 0);
    accA = __builtin_amdgcn_mfma_f32_16x16x32_bf16(a1, bA1, accA, 0, 0, 0);
    accB = __builtin_amdgcn_mfma_f32_16x16x32_bf16(a1, bB1, accB, 0, 0, 0);
    accA = __builtin_amdgcn_mfma_f32_16x16x32_bf16(a2, bA0, accA, 0, 0, 0);
    accB = __builtin_amdgcn_mfma_f32_16x16x32_bf16(a2, bB0, accB, 0, 0, 0);
    accA = __builtin_amdgcn_mfma_f32_16x16x32_bf16(a3, bA1, accA, 0, 0, 0);
    accB = __builtin_amdgcn_mfma_f32_16x16x32_bf16(a3, bB1, accB, 0, 0, 0);
    accA = __builtin_amdgcn_mfma_f32_16x16x32_bf16(a0, bA2, accA, 0, 0, 0);
    accB = __builtin_amdgcn_mfma_f32_16x16x32_bf16(a0, bB2, accB, 0, 0, 0);
    accA = __builtin_amdgcn_mfma_f32_16x16x32_bf16(a1, bA3, accA, 0, 0, 0);
    accB = __builtin_amdgcn_mfma_f32_16x16x32_bf16(a1, bB3, accB, 0, 0, 0);

    // fold with exact per-lane top-2; strict < + ascending scan keeps lowest k
#pragma unroll
    for (int reg = 0; reg < 4; ++reg) {
      {
        float d = fmaf(-2.0f, accA[reg], rzv[reg] + enA);
        int k = kb + col;
        bool w1 = d < b1d[reg];
        bool w2 = d < b2d[reg];
        b2d[reg] = w1 ? b1d[reg] : (w2 ? d : b2d[reg]);
        b2k[reg] = w1 ? b1k[reg] : (w2 ? k : b2k[reg]);
        b1d[reg] = w1 ? d : b1d[reg];
        b1k[reg] = w1 ? k : b1k[reg];
      }
      {
        float d = fmaf(-2.0f, accB[reg], rzv[reg] + enB);
        int k = kb + 16 + col;
        bool w1 = d < b1d[reg];
        bool w2 = d < b2d[reg];
        b2d[reg] = w1 ? b1d[reg] : (w2 ? d : b2d[reg]);
        b2k[reg] = w1 ? b1k[reg] : (w2 ? k : b2k[reg]);
        b1d[reg] = w1 ? d : b1d[reg];
        b1k[reg] = w1 ? k : b1k[reg];
      }
    }
  };

  // ---- K-loop: 32 tiles, barrier-free, 1-tile-ahead reg prefetch.
  // Named sets X (even tiles) / Y (odd tiles) -- static indexing only.
  short8 xA0, xA1, xA2, xA3, xB0, xB1, xB2, xB3;
  short8 yA0, yA1, yA2, yA3, yB0, yB1, yB2, yB3;
  load_tile(0, xA0, xA1, xA2, xA3, xB0, xB1, xB2, xB3);
  for (int t = 0; t < NT; t += 2) {
    load_tile((t + 1) * TC, yA0, yA1, yA2, yA3, yB0, yB1, yB2, yB3);
    compute_tile(t * TC, xA0, xA1, xA2, xA3, xB0, xB1, xB2, xB3);
    if (t + 2 < NT) {
      load_tile((t + 2) * TC, xA0, xA1, xA2, xA3, xB0, xB1, xB2, xB3);
    }
    compute_tile((t + 1) * TC, yA0, yA1, yA2, yA3, yB0, yB1, yB2, yB3);
  }

  // ---- cross-lane top-2 butterfly over the 16 col-classes (within quad group)
#pragma unroll
  for (int m = 1; m < 16; m <<= 1) {
#pragma unroll
    for (int reg = 0; reg < 4; ++reg) {
      float od1 = __shfl_xor(b1d[reg], m, 64);
      int ok1 = __shfl_xor(b1k[reg], m, 64);
      float od2 = __shfl_xor(b2d[reg], m, 64);
      int ok2 = __shfl_xor(b2k[reg], m, 64);
      bool fo = (od1 < b1d[reg]) || (od1 == b1d[reg] && ok1 < b1k[reg]);
      float w1 = fo ? od1 : b1d[reg];
      int wk1 = fo ? ok1 : b1k[reg];
      float l1 = fo ? b1d[reg] : od1;
      int lk1 = fo ? b1k[reg] : ok1;
      bool so = (od2 < b2d[reg]) || (od2 == b2d[reg] && ok2 < b2k[reg]);
      float m2 = so ? od2 : b2d[reg];
      int mk2 = so ? ok2 : b2k[reg];
      bool lw = (l1 < m2) || (l1 == m2 && lk1 < mk2);
      b1d[reg] = w1;
      b1k[reg] = wk1;
      b2d[reg] = lw ? l1 : m2;
      b2k[reg] = lw ? lk1 : mk2;
    }
  }

  // writer lanes: col<4 handles row = wav*16 + quad*4 + col (using reg=col)
  if (col < 4) {
    const int row = wav * 16 + quad * 4 + col;
    float bd1 = b1d[col], bd2 = b2d[col];
    int bk1 = b1k[col], bk2 = b2k[col];
    if (bd2 - bd1 < 1e-5f) {
      // exact fp32 recompute (R3 arithmetic) of the top-2 candidates
      const int grow = rowbase + row;
      const float4* zp = (const float4*)(z + (size_t)grow * D);
      float s0 = 0.f, s1 = 0.f, s2 = 0.f, s3 = 0.f;
#pragma unroll
      for (int i = 0; i < 16; ++i) {
        float4 v = zp[i];
        s0 = fmaf(v.x, v.x, s0);
        s1 = fmaf(v.y, v.y, s1);
        s2 = fmaf(v.z, v.z, s2);
        s3 = fmaf(v.w, v.w, s3);
      }
      const float rzx = (s0 + s1) + (s2 + s3);
      float dx[2];
      int kk[2] = {bk1, bk2};
#pragma unroll
      for (int c = 0; c < 2; ++c) {
        const float4* e4 = (const float4*)(cb + (size_t)kk[c] * D);
        float d0 = 0.f, d1 = 0.f, d2 = 0.f, d3 = 0.f;
#pragma unroll
        for (int i = 0; i < 16; ++i) {
          float4 v = e4[i];
          float4 zv = zp[i];
          d0 = fmaf(zv.x, v.x, d0);
          d1 = fmaf(zv.y, v.y, d1);
          d2 = fmaf(zv.z, v.z, d2);
          d3 = fmaf(zv.w, v.w, d3);
        }
        float dot = (d0 + d1) + (d2 + d3);
        dx[c] = (rzx + scbn[kk[c]]) - 2.0f * dot;
      }
      if ((dx[1] < dx[0]) || (dx[1] == dx[0] && bk2 < bk1)) bk1 = bk2;
    }
    skf[row] = bk1;
    out_idx[rowbase + row] = (float)bk1;
    atomicAdd(&lhist[bk1], 1u);
  }
  __syncthreads();

  // ---- flush per-block histogram: one global atomic per distinct code
#pragma unroll
  for (int j = 0; j < KC / 256; ++j) {
    unsigned int c = lhist[tid + 256 * j];
    if (c) atomicAdd(&hist[tid + 256 * j], c);
  }

  // ---- epilogue: quantized write (exact fp32 codebook rows) + loss partial
  float lsum = 0.f;
#pragma unroll
  for (int it = 0; it < 4; ++it) {
    int f4 = it * 256 + tid;
    int r = f4 >> 4;
    int c4 = (f4 & 15) * 4;
    int bk = skf[r];
    const float4 q = *(const float4*)(cb + (size_t)bk * D + c4);
    const int grow = rowbase + r;
    const float4 zv = *(const float4*)(z + (size_t)grow * D + c4);
    *(float4*)(out_q + (size_t)grow * D + c4) = q;
    float ax = q.x - zv.x, ay = q.y - zv.y, az = q.z - zv.z, aw = q.w - zv.w;
    lsum += ax * ax + ay * ay + az * az + aw * aw;
  }
#pragma unroll
  for (int off = 32; off > 0; off >>= 1) lsum += __shfl_down(lsum, off, 64);
  if (lane == 0) swav[wav] = lsum;
  __syncthreads();
  if (tid == 0) {
    atomicAdd(loss_acc, (swav[0] + swav[1]) + (swav[2] + swav[3]));
  }
}

__global__ __launch_bounds__(1024) void vq_final(
    const unsigned int* __restrict__ hist, const float* __restrict__ loss_acc,
    float* __restrict__ out_loss, float* __restrict__ out_perp, float inv_n,
    float inv_nd) {
  __shared__ float part[16];
  const int t = threadIdx.x;
  const int lane = t & 63;
  const int wav = t >> 6;
  float p = (float)hist[t] * inv_n;
  float v = p * logf(p + 1e-10f);
#pragma unroll
  for (int off = 32; off > 0; off >>= 1) v += __shfl_down(v, off, 64);
  if (lane == 0) part[wav] = v;
  __syncthreads();
  if (t == 0) {
    float s = 0.f;
#pragma unroll
    for (int j = 0; j < 16; ++j) s += part[j];
    *out_perp = expf(-s);
    // q_latent + 0.25*e_latent, both numerically mean((q-z)^2)
    *out_loss = 1.25f * loss_acc[0] * inv_nd;
  }
}

extern "C" void kernel_launch(void* const* d_in, const int* in_sizes, int n_in,
                              void* d_out, int out_size, void* d_ws,
                              size_t ws_size, hipStream_t stream) {
  (void)n_in;
  (void)out_size;
  (void)ws_size;
  const float* z = (const float*)d_in[0];
  const float* cb = (const float*)d_in[1];
  const int N = in_sizes[0] / D;  // 32768

  // Output layout (flat float32, reference return order):
  float* out_q = (float*)d_out;                     // N*D
  float* out_loss = (float*)d_out + (size_t)N * D;  // 1
  float* out_idx = out_loss + 1;                    // N
  float* out_perp = out_idx + N;                    // 1

  // Workspace (floats): hist[1024] @0, loss_acc @1024, cbn[1024] @1040,
  // bsplit (short[1024*128]) @ float-idx 2064 (byte 8256, 16B-aligned).
  unsigned int* hist = (unsigned int*)d_ws;
  float* loss_acc = (float*)d_ws + 1024;
  float* cbn = (float*)d_ws + 1040;
  unsigned short* bsplit = (unsigned short*)((float*)d_ws + 2064);

  vq_prep<<<dim3(KC / 256), dim3(256), 0, stream>>>(cb, bsplit, cbn, hist,
                                                    loss_acc);
  vq_main<<<dim3(N / ROWS), dim3(256), 0, stream>>>(z, bsplit, cbn, cb, out_q,
                                                    out_idx, hist, loss_acc);
  vq_final<<<dim3(1), dim3(1024), 0, stream>>>(
      hist, loss_acc, out_loss, out_perp, 1.0f / (float)N,
      1.0f / ((float)N * (float)D));
}

// Round 8
// 101.568 us; speedup vs baseline: 1.3122x; 1.3122x over previous
//
#include <hip/hip_runtime.h>
#include <math.h>

// VQ-VAE vector quantizer for MI355X (gfx950).
// z: [32768, 64] fp32, codebook: [1024, 64] fp32.
// Outputs (flat float32, concatenated): quantized_st [32768*64], vq_loss [1],
// indices [32768] (as float), perplexity [1].
//
// R18: bottleneck finally identified from R16/R17 counters: the R13-family
// loop is LDS-BANDWIDTH-bound. Per CU per phase: 8 waves x (16 ds_read_b128
// + 4 ds_write_b128) ~= 1920cy + ~512cy measured bank-conflict cycles =
// ~85% of the 2850cy phase. Explains all nulls (occupancy/prefetch/barrier
// removal don't cut LDS traffic). R17's global-gather alternative: 71us
// (latency-exposed at 2 waves/SIMD) -- reconfirms R10's lesson, LDS staging
// stays. R18 halves LDS reads PER ROW: wave (g,h) owns 32 rows (two 16-row
// sets sharing one tile's B-frags, 24 MFMAs/phase) and HALF the codebook
// (tile parity h -> 8 ds_reads/phase, was 16). Cross-parity top-2 merge at
// the end (R11/R14-verified code). Staging/slots/barriers/fold/butterfly/
// recheck = R13 verbatim. LDS 43.3KB -> 2 blocks/CU; no tight VGPR caps.
// Numerics: 3-term split-bf16 + exact fp32 recheck (margin 1e-5), unchanged.

#define D 64
#define KC 1024
#define ROWS 64           // rows per block (2 row-groups x 32)
#define TC 32             // codes per LDS tile
#define NT (KC / TC)      // 32 tiles
#define NP (NT / 2)       // 16 pair-phases
#define BCH 33            // chunk stride (16B chunks) for bank-conflict-free B
#define TILE_SH (16 * BCH * 8)  // 4224 shorts per tile slot

typedef short short8 __attribute__((ext_vector_type(8)));
typedef short short4v __attribute__((ext_vector_type(4)));
typedef float f32x4 __attribute__((ext_vector_type(4)));

__device__ __forceinline__ unsigned short f2bf(float x) {
  unsigned int u = __float_as_uint(x);
  unsigned int r = (u + 0x7fffu + ((u >> 16) & 1u)) >> 16;
  return (unsigned short)r;
}
__device__ __forceinline__ float bf2f(unsigned short h) {
  return __uint_as_float((unsigned int)h << 16);
}

// split two float4 (8 floats) into hi/lo bf16 short8
__device__ __forceinline__ void split8(const float4 a, const float4 b,
                                       short8* hi, short8* lo) {
  float f[8] = {a.x, a.y, a.z, a.w, b.x, b.y, b.z, b.w};
#pragma unroll
  for (int i = 0; i < 8; ++i) {
    unsigned short h = f2bf(f[i]);
    (*hi)[i] = (short)h;
    (*lo)[i] = (short)f2bf(f[i] - bf2f(h));
  }
}

// Precompute: exact fp32 code norms, split-bf16 codebook
// bsplit[k][128] = [e_hi(64) | e_lo(64)], zero hist/loss.
__global__ __launch_bounds__(256) void vq_prep(
    const float* __restrict__ cb, unsigned short* __restrict__ bsplit,
    float* __restrict__ cbn, unsigned int* __restrict__ hist,
    float* __restrict__ loss_acc) {
  const int k = blockIdx.x * 256 + threadIdx.x;  // 0..1023
  const float4* e = (const float4*)(cb + (size_t)k * D);
  unsigned short* bp = bsplit + (size_t)k * 128;
  float s0 = 0.f, s1 = 0.f, s2 = 0.f, s3 = 0.f;
#pragma unroll
  for (int i = 0; i < 16; ++i) {
    float4 v = e[i];
    s0 = fmaf(v.x, v.x, s0);
    s1 = fmaf(v.y, v.y, s1);
    s2 = fmaf(v.z, v.z, s2);
    s3 = fmaf(v.w, v.w, s3);
    unsigned short h0 = f2bf(v.x), h1 = f2bf(v.y), h2 = f2bf(v.z), h3 = f2bf(v.w);
    short4v hv = {(short)h0, (short)h1, (short)h2, (short)h3};
    short4v lv = {(short)f2bf(v.x - bf2f(h0)), (short)f2bf(v.y - bf2f(h1)),
                  (short)f2bf(v.z - bf2f(h2)), (short)f2bf(v.w - bf2f(h3))};
    *(short4v*)(bp + i * 4) = hv;
    *(short4v*)(bp + 64 + i * 4) = lv;
  }
  cbn[k] = (s0 + s1) + (s2 + s3);
  hist[k] = 0u;
  if (k == 0) loss_acc[0] = 0.f;
}

__global__ __launch_bounds__(256, 2) void vq_main(
    const float* __restrict__ z, const unsigned short* __restrict__ bsplit,
    const float* __restrict__ cbn, const float* __restrict__ cb,
    float* __restrict__ out_q, float* __restrict__ out_idx,
    unsigned int* __restrict__ hist, float* __restrict__ loss_acc) {
  // B double buffer of tile PAIRS: [buf][tile-in-pair][16 chunk-rows x 33].
  __shared__ __align__(16) unsigned short Bsh[2][2][TILE_SH];
  __shared__ float scbn[KC];
  __shared__ int skf[ROWS];
  __shared__ float swav[4];
  __shared__ unsigned int lhist[KC];
  __shared__ float md1[ROWS], md2[ROWS];
  __shared__ int mk1s[ROWS], mk2s[ROWS];

  const int tid = threadIdx.x;
  const int lane = tid & 63;
  const int wav = tid >> 6;
  const int g = wav >> 1;  // row-group 0..1 (32 rows each)
  const int h = wav & 1;   // tile parity 0..1 (code half)
  const int quad = lane >> 4;
  const int col = lane & 15;
  const int rowbase = blockIdx.x * ROWS;

  // ---- prologue
  // Direct A-fragment z loads for BOTH 16-row sets of this wave:
  // set0 row = g*32+col, set1 row = g*32+16+col; dims quad*8..+8, 32+quad*8..+8.
  const int arow0 = rowbase + g * 32 + col;
  const float4* zr0 = (const float4*)(z + (size_t)arow0 * D);
  const float4* zr1 = (const float4*)(z + (size_t)(arow0 + 16) * D);
  const float4 u0 = zr0[quad * 2];
  const float4 u1 = zr0[quad * 2 + 1];
  const float4 u2 = zr0[8 + quad * 2];
  const float4 u3 = zr0[8 + quad * 2 + 1];
  const float4 v0 = zr1[quad * 2];
  const float4 v1 = zr1[quad * 2 + 1];
  const float4 v2 = zr1[8 + quad * 2];
  const float4 v3 = zr1[8 + quad * 2 + 1];

  // cbn -> LDS, zero lhist
  *(float4*)&scbn[tid * 4] = *(const float4*)&cbn[tid * 4];
#pragma unroll
  for (int j = 0; j < KC / 256; ++j) lhist[tid + 256 * j] = 0u;

  // stage pair 0: per tile, thread t moves global chunks t and t+256.
  // chunk c: code k=c>>4, plane-chunk jj=c&15; LDS slot = jj*BCH + k.
  const int cslot = (tid & 15) * BCH + (tid >> 4);  // slot for chunk tid
#pragma unroll
  for (int T = 0; T < 2; ++T) {
    const size_t off =
        (size_t)(T * TC + (tid >> 4)) * 128 + (size_t)(tid & 15) * 8;
    short8 s0 = *(const short8*)(bsplit + off);
    short8 s1 = *(const short8*)(bsplit + off + 2048);  // +16 codes
    *(short8*)&Bsh[0][T][cslot * 8] = s0;
    *(short8*)&Bsh[0][T][(cslot + 16) * 8] = s1;
  }

  // in-register split-bf16 A-frags, both sets
  short8 x0, x1, x2, x3, y0, y1, y2, y3;
  split8(u0, u1, &x0, &x2);  // set0: z_hi/z_lo, k = quad*8 .. +8
  split8(u2, u3, &x1, &x3);  // set0: z_hi/z_lo, k = 32+quad*8 .. +8
  split8(v0, v1, &y0, &y2);  // set1
  split8(v2, v3, &y1, &y3);

  // row norms (row-constant -> cancels in comparisons; recheck is exact)
  float n0 = ((u0.x * u0.x + u0.y * u0.y) + (u0.z * u0.z + u0.w * u0.w)) +
             ((u1.x * u1.x + u1.y * u1.y) + (u1.z * u1.z + u1.w * u1.w)) +
             ((u2.x * u2.x + u2.y * u2.y) + (u2.z * u2.z + u2.w * u2.w)) +
             ((u3.x * u3.x + u3.y * u3.y) + (u3.z * u3.z + u3.w * u3.w));
  float n1 = ((v0.x * v0.x + v0.y * v0.y) + (v0.z * v0.z + v0.w * v0.w)) +
             ((v1.x * v1.x + v1.y * v1.y) + (v1.z * v1.z + v1.w * v1.w)) +
             ((v2.x * v2.x + v2.y * v2.y) + (v2.z * v2.z + v2.w * v2.w)) +
             ((v3.x * v3.x + v3.y * v3.y) + (v3.z * v3.z + v3.w * v3.w));
  n0 += __shfl_xor(n0, 16, 64);
  n0 += __shfl_xor(n0, 32, 64);
  n1 += __shfl_xor(n1, 16, 64);
  n1 += __shfl_xor(n1, 32, 64);
  float rzv0[4], rzv1[4];
#pragma unroll
  for (int r = 0; r < 4; ++r) {
    rzv0[r] = __shfl(n0, quad * 4 + r, 64);
    rzv1[r] = __shfl(n1, quad * 4 + r, 64);
  }

  __syncthreads();  // covers pair-0 ds_writes + scbn + lhist

  // per-lane exact top-2, per row-set, over this wave's code half
  float b1d0[4], b2d0[4], b1d1[4], b2d1[4];
  int b1k0[4], b2k0[4], b1k1[4], b2k1[4];
#pragma unroll
  for (int i = 0; i < 4; ++i) {
    b1d0[i] = 3.4e38f; b2d0[i] = 3.4e38f;
    b1k0[i] = 0x7fffffff; b2k0[i] = 0x7fffffff;
    b1d1[i] = 3.4e38f; b2d1[i] = 3.4e38f;
    b1k1[i] = 0x7fffffff; b2k1[i] = 0x7fffffff;
  }

  // top-2 fold step (strict < + ascending scan keeps lowest k)
  auto fold = [&](float (&B1D)[4], int (&B1K)[4], float (&B2D)[4],
                  int (&B2K)[4], float d, int k, int reg) {
    bool w1 = d < B1D[reg];
    bool w2 = d < B2D[reg];
    B2D[reg] = w1 ? B1D[reg] : (w2 ? d : B2D[reg]);
    B2K[reg] = w1 ? B1K[reg] : (w2 ? k : B2K[reg]);
    B1D[reg] = w1 ? d : B1D[reg];
    B1K[reg] = w1 ? k : B1K[reg];
  };

  // ---- K-loop: 16 pair-phases; wave computes ONLY its parity tile (8
  // ds_reads), against BOTH row-sets (24 MFMAs). Staging cooperative.
  for (int p = 0; p < NP; ++p) {
    // stage next pair: global -> regs (lands during this phase's compute)
    short8 st00, st01, st10, st11;
    if (p + 1 < NP) {
      const size_t base = (size_t)((p + 1) * 2) * TC;
      const size_t o0 = (base + (tid >> 4)) * 128 + (size_t)(tid & 15) * 8;
      st00 = *(const short8*)(bsplit + o0);
      st01 = *(const short8*)(bsplit + o0 + 2048);
      st10 = *(const short8*)(bsplit + o0 + 4096);  // +32 codes (tile 1)
      st11 = *(const short8*)(bsplit + o0 + 6144);
    }

    const int kb = (p * 2 + h) * TC;
    const unsigned short* bcur = &Bsh[p & 1][h][0];
    const float enA = scbn[kb + col];
    const float enB = scbn[kb + 16 + col];
    // B-frags: chain A = code col, chain B = code col+16.
    // frag i lives at chunk-row i*4+quad, slot = row*BCH + code.
    const short8 bA0 = *(const short8*)(bcur + ((0 + quad) * BCH + col) * 8);
    const short8 bA1 = *(const short8*)(bcur + ((4 + quad) * BCH + col) * 8);
    const short8 bA2 = *(const short8*)(bcur + ((8 + quad) * BCH + col) * 8);
    const short8 bA3 = *(const short8*)(bcur + ((12 + quad) * BCH + col) * 8);
    const short8 bB0 = *(const short8*)(bcur + ((0 + quad) * BCH + col + 16) * 8);
    const short8 bB1 = *(const short8*)(bcur + ((4 + quad) * BCH + col + 16) * 8);
    const short8 bB2 = *(const short8*)(bcur + ((8 + quad) * BCH + col + 16) * 8);
    const short8 bB3 = *(const short8*)(bcur + ((12 + quad) * BCH + col + 16) * 8);

    // 4 independent accumulators: {set0,set1} x {chainA,chainB}
    f32x4 aA0 = {0.f, 0.f, 0.f, 0.f}, aB0 = {0.f, 0.f, 0.f, 0.f};
    f32x4 aA1 = {0.f, 0.f, 0.f, 0.f}, aB1 = {0.f, 0.f, 0.f, 0.f};
    // 3-term split: hi.hi + lo.hi + hi.lo
    aA0 = __builtin_amdgcn_mfma_f32_16x16x32_bf16(x0, bA0, aA0, 0, 0, 0);
    aB0 = __builtin_amdgcn_mfma_f32_16x16x32_bf16(x0, bB0, aB0, 0, 0, 0);
    aA1 = __builtin_amdgcn_mfma_f32_16x16x32_bf16(y0, bA0, aA1, 0, 0, 0);
    aB1 = __builtin_amdgcn_mfma_f32_16x16x32_bf16(y0, bB0, aB1, 0, 0, 0);
    aA0 = __builtin_amdgcn_mfma_f32_16x16x32_bf16(x1, bA1, aA0, 0, 0, 0);
    aB0 = __builtin_amdgcn_mfma_f32_16x16x32_bf16(x1, bB1, aB0, 0, 0, 0);
    aA1 = __builtin_amdgcn_mfma_f32_16x16x32_bf16(y1, bA1, aA1, 0, 0, 0);
    aB1 = __builtin_amdgcn_mfma_f32_16x16x32_bf16(y1, bB1, aB1, 0, 0, 0);
    aA0 = __builtin_amdgcn_mfma_f32_16x16x32_bf16(x2, bA0, aA0, 0, 0, 0);
    aB0 = __builtin_amdgcn_mfma_f32_16x16x32_bf16(x2, bB0, aB0, 0, 0, 0);
    aA1 = __builtin_amdgcn_mfma_f32_16x16x32_bf16(y2, bA0, aA1, 0, 0, 0);
    aB1 = __builtin_amdgcn_mfma_f32_16x16x32_bf16(y2, bB0, aB1, 0, 0, 0);
    aA0 = __builtin_amdgcn_mfma_f32_16x16x32_bf16(x3, bA1, aA0, 0, 0, 0);
    aB0 = __builtin_amdgcn_mfma_f32_16x16x32_bf16(x3, bB1, aB0, 0, 0, 0);
    aA1 = __builtin_amdgcn_mfma_f32_16x16x32_bf16(y3, bA1, aA1, 0, 0, 0);
    aB1 = __builtin_amdgcn_mfma_f32_16x16x32_bf16(y3, bB1, aB1, 0, 0, 0);
    aA0 = __builtin_amdgcn_mfma_f32_16x16x32_bf16(x0, bA2, aA0, 0, 0, 0);
    aB0 = __builtin_amdgcn_mfma_f32_16x16x32_bf16(x0, bB2, aB0, 0, 0, 0);
    aA1 = __builtin_amdgcn_mfma_f32_16x16x32_bf16(y0, bA2, aA1, 0, 0, 0);
    aB1 = __builtin_amdgcn_mfma_f32_16x16x32_bf16(y0, bB2, aB1, 0, 0, 0);
    aA0 = __builtin_amdgcn_mfma_f32_16x16x32_bf16(x1, bA3, aA0, 0, 0, 0);
    aB0 = __builtin_amdgcn_mfma_f32_16x16x32_bf16(x1, bB3, aB0, 0, 0, 0);
    aA1 = __builtin_amdgcn_mfma_f32_16x16x32_bf16(y1, bA3, aA1, 0, 0, 0);
    aB1 = __builtin_amdgcn_mfma_f32_16x16x32_bf16(y1, bB3, aB1, 0, 0, 0);

#pragma unroll
    for (int reg = 0; reg < 4; ++reg) {
      fold(b1d0, b1k0, b2d0, b2k0, fmaf(-2.0f, aA0[reg], rzv0[reg] + enA),
           kb + col, reg);
      fold(b1d0, b1k0, b2d0, b2k0, fmaf(-2.0f, aB0[reg], rzv0[reg] + enB),
           kb + 16 + col, reg);
      fold(b1d1, b1k1, b2d1, b2k1, fmaf(-2.0f, aA1[reg], rzv1[reg] + enA),
           kb + col, reg);
      fold(b1d1, b1k1, b2d1, b2k1, fmaf(-2.0f, aB1[reg], rzv1[reg] + enB),
           kb + 16 + col, reg);
    }

    // commit staged regs to the other pair buffer, then barrier
    if (p + 1 < NP) {
      unsigned short* bn0 = &Bsh[(p + 1) & 1][0][0];
      unsigned short* bn1 = &Bsh[(p + 1) & 1][1][0];
      *(short8*)&bn0[cslot * 8] = st00;
      *(short8*)&bn0[(cslot + 16) * 8] = st01;
      *(short8*)&bn1[cslot * 8] = st10;
      *(short8*)&bn1[(cslot + 16) * 8] = st11;
    }
    __syncthreads();
  }

  // ---- cross-lane top-2 butterfly over the 16 col-classes (within quad
  // group), per row-set (R13 verbatim)
  auto butterfly = [&](float (&B1D)[4], int (&B1K)[4], float (&B2D)[4],
                       int (&B2K)[4]) {
#pragma unroll
    for (int m = 1; m < 16; m <<= 1) {
#pragma unroll
      for (int reg = 0; reg < 4; ++reg) {
        float od1 = __shfl_xor(B1D[reg], m, 64);
        int ok1 = __shfl_xor(B1K[reg], m, 64);
        float od2 = __shfl_xor(B2D[reg], m, 64);
        int ok2 = __shfl_xor(B2K[reg], m, 64);
        bool fo = (od1 < B1D[reg]) || (od1 == B1D[reg] && ok1 < B1K[reg]);
        float w1 = fo ? od1 : B1D[reg];
        int wk1 = fo ? ok1 : B1K[reg];
        float l1 = fo ? B1D[reg] : od1;
        int lk1 = fo ? B1K[reg] : ok1;
        bool so = (od2 < B2D[reg]) || (od2 == B2D[reg] && ok2 < B2K[reg]);
        float m2 = so ? od2 : B2D[reg];
        int mk2 = so ? ok2 : B2K[reg];
        bool lw = (l1 < m2) || (l1 == m2 && lk1 < mk2);
        B1D[reg] = w1;
        B1K[reg] = wk1;
        B2D[reg] = lw ? l1 : m2;
        B2K[reg] = lw ? lk1 : mk2;
      }
    }
  };
  butterfly(b1d0, b1k0, b2d0, b2k0);
  butterfly(b1d1, b1k1, b2d1, b2k1);

  // merge + margin-recheck + outputs for one row (h==0 writers)
  auto finish_row = [&](int row, float bd1, int bk1, float bd2, int bk2) {
    // cross-parity merge with h==1's published top-2 (R11/R14-verified)
    {
      float od1 = md1[row];
      int ok1 = mk1s[row];
      float od2 = md2[row];
      int ok2 = mk2s[row];
      bool fo = (od1 < bd1) || (od1 == bd1 && ok1 < bk1);
      float w1 = fo ? od1 : bd1;
      int wk1 = fo ? ok1 : bk1;
      float l1 = fo ? bd1 : od1;
      int lk1 = fo ? bk1 : ok1;
      bool so = (od2 < bd2) || (od2 == bd2 && ok2 < bk2);
      float m2 = so ? od2 : bd2;
      int mk2v = so ? ok2 : bk2;
      bool lw = (l1 < m2) || (l1 == m2 && lk1 < mk2v);
      bd1 = w1;
      bk1 = wk1;
      bd2 = lw ? l1 : m2;
      bk2 = lw ? lk1 : mk2v;
    }
    if (bd2 - bd1 < 1e-5f) {
      // exact fp32 recompute (R3 arithmetic) of the top-2 candidates
      const int grow = rowbase + row;
      const float4* zp = (const float4*)(z + (size_t)grow * D);
      float s0 = 0.f, s1 = 0.f, s2 = 0.f, s3 = 0.f;
#pragma unroll
      for (int i = 0; i < 16; ++i) {
        float4 v = zp[i];
        s0 = fmaf(v.x, v.x, s0);
        s1 = fmaf(v.y, v.y, s1);
        s2 = fmaf(v.z, v.z, s2);
        s3 = fmaf(v.w, v.w, s3);
      }
      const float rzx = (s0 + s1) + (s2 + s3);
      float dx[2];
      int kk[2] = {bk1, bk2};
#pragma unroll
      for (int c = 0; c < 2; ++c) {
        const float4* e4 = (const float4*)(cb + (size_t)kk[c] * D);
        float d0 = 0.f, d1 = 0.f, d2 = 0.f, d3 = 0.f;
#pragma unroll
        for (int i = 0; i < 16; ++i) {
          float4 v = e4[i];
          float4 zv = zp[i];
          d0 = fmaf(zv.x, v.x, d0);
          d1 = fmaf(zv.y, v.y, d1);
          d2 = fmaf(zv.z, v.z, d2);
          d3 = fmaf(zv.w, v.w, d3);
        }
        float dot = (d0 + d1) + (d2 + d3);
        dx[c] = (rzx + scbn[kk[c]]) - 2.0f * dot;
      }
      if ((dx[1] < dx[0]) || (dx[1] == dx[0] && bk2 < bk1)) bk1 = bk2;
    }
    skf[row] = bk1;
    out_idx[rowbase + row] = (float)bk1;
    atomicAdd(&lhist[bk1], 1u);
  };

  // ---- cross-parity: h==1 publishes both row-sets, h==0 merges + finishes
  if (h == 1 && col < 4) {
    const int row0 = g * 32 + quad * 4 + col;
    md1[row0] = b1d0[col];
    mk1s[row0] = b1k0[col];
    md2[row0] = b2d0[col];
    mk2s[row0] = b2k0[col];
    const int row1 = row0 + 16;
    md1[row1] = b1d1[col];
    mk1s[row1] = b1k1[col];
    md2[row1] = b2d1[col];
    mk2s[row1] = b2k1[col];
  }
  __syncthreads();
  if (h == 0 && col < 4) {
    finish_row(g * 32 + quad * 4 + col, b1d0[col], b1k0[col], b2d0[col],
               b2k0[col]);
    finish_row(g * 32 + 16 + quad * 4 + col, b1d1[col], b1k1[col], b2d1[col],
               b2k1[col]);
  }
  __syncthreads();

  // ---- flush per-block histogram: one global atomic per distinct code
#pragma unroll
  for (int j = 0; j < KC / 256; ++j) {
    unsigned int c = lhist[tid + 256 * j];
    if (c) atomicAdd(&hist[tid + 256 * j], c);
  }

  // ---- epilogue: quantized write (exact fp32 codebook rows) + loss partial
  float lsum = 0.f;
#pragma unroll
  for (int it = 0; it < 4; ++it) {
    int f4 = it * 256 + tid;
    int r = f4 >> 4;
    int c4 = (f4 & 15) * 4;
    int bk = skf[r];
    const float4 q = *(const float4*)(cb + (size_t)bk * D + c4);
    const int grow = rowbase + r;
    const float4 zv = *(const float4*)(z + (size_t)grow * D + c4);
    *(float4*)(out_q + (size_t)grow * D + c4) = q;
    float ax = q.x - zv.x, ay = q.y - zv.y, az = q.z - zv.z, aw = q.w - zv.w;
    lsum += ax * ax + ay * ay + az * az + aw * aw;
  }
#pragma unroll
  for (int off = 32; off > 0; off >>= 1) lsum += __shfl_down(lsum, off, 64);
  if (lane == 0) swav[wav] = lsum;
  __syncthreads();
  if (tid == 0) {
    atomicAdd(loss_acc, (swav[0] + swav[1]) + (swav[2] + swav[3]));
  }
}

__global__ __launch_bounds__(1024) void vq_final(
    const unsigned int* __restrict__ hist, const float* __restrict__ loss_acc,
    float* __restrict__ out_loss, float* __restrict__ out_perp, float inv_n,
    float inv_nd) {
  __shared__ float part[16];
  const int t = threadIdx.x;
  const int lane = t & 63;
  const int wav = t >> 6;
  float p = (float)hist[t] * inv_n;
  float v = p * logf(p + 1e-10f);
#pragma unroll
  for (int off = 32; off > 0; off >>= 1) v += __shfl_down(v, off, 64);
  if (lane == 0) part[wav] = v;
  __syncthreads();
  if (t == 0) {
    float s = 0.f;
#pragma unroll
    for (int j = 0; j < 16; ++j) s += part[j];
    *out_perp = expf(-s);
    // q_latent + 0.25*e_latent, both numerically mean((q-z)^2)
    *out_loss = 1.25f * loss_acc[0] * inv_nd;
  }
}

extern "C" void kernel_launch(void* const* d_in, const int* in_sizes, int n_in,
                              void* d_out, int out_size, void* d_ws,
                              size_t ws_size, hipStream_t stream) {
  (void)n_in;
  (void)out_size;
  (void)ws_size;
  const float* z = (const float*)d_in[0];
  const float* cb = (const float*)d_in[1];
  const int N = in_sizes[0] / D;  // 32768

  // Output layout (flat float32, reference return order):
  float* out_q = (float*)d_out;                     // N*D
  float* out_loss = (float*)d_out + (size_t)N * D;  // 1
  float* out_idx = out_loss + 1;                    // N
  float* out_perp = out_idx + N;                    // 1

  // Workspace (floats): hist[1024] @0, loss_acc @1024, cbn[1024] @1040,
  // bsplit (short[1024*128]) @ float-idx 2064 (byte 8256, 16B-aligned).
  unsigned int* hist = (unsigned int*)d_ws;
  float* loss_acc = (float*)d_ws + 1024;
  float* cbn = (float*)d_ws + 1040;
  unsigned short* bsplit = (unsigned short*)((float*)d_ws + 2064);

  vq_prep<<<dim3(KC / 256), dim3(256), 0, stream>>>(cb, bsplit, cbn, hist,
                                                    loss_acc);
  vq_main<<<dim3(N / ROWS), dim3(256), 0, stream>>>(z, bsplit, cbn, cb, out_q,
                                                    out_idx, hist, loss_acc);
  vq_final<<<dim3(1), dim3(1024), 0, stream>>>(
      hist, loss_acc, out_loss, out_perp, 1.0f / (float)N,
      1.0f / ((float)N * (float)D));
}

// Round 9
// 98.879 us; speedup vs baseline: 1.3479x; 1.0272x over previous
//
#include <hip/hip_runtime.h>
#include <math.h>

// VQ-VAE vector quantizer for MI355X (gfx950).
// z: [32768, 64] fp32, codebook: [1024, 64] fp32.
// Outputs (flat float32, concatenated): quantized_st [32768*64], vq_loss [1],
// indices [32768] (as float), perplexity [1].
//
// R19: R18's null kills the LDS-BW model (halved reads, no change; pipe was
// ~26% busy -- 12cy/instr was per-wave latency, not pipe occupancy). Ledger:
// every single-resource lever nulled; only PHASE COUNT ever moved vq_main
// (R12: 32->16 phases, -4us). The phase is a serial chain: barrier ->
// ds_read latency -> 6-deep MFMA -> 16-deep serial fold -> staged drain ->
// barrier, at 2 waves/SIMD. R19 attacks the two untouched links on the
// verified R13 skeleton: (1) phases 16->8 via tile-QUAD double buffer
// (4 tiles/phase, LDS 76KB, still 2 blocks/CU, +16 staged VGPRs, no caps);
// (2) fold chain split: tiles {0,1}->state A, {2,3}->state B (two 8-deep
// chains, ILP 2), merged in-register at loop exit (verified merge logic).
// Everything else (staging slots, fold semantics, butterfly, recheck,
// epilogue, separate vq_final) = R13 verbatim.
// Numerics: 3-term split-bf16 + exact fp32 recheck (margin 1e-5), unchanged.

#define D 64
#define KC 1024
#define ROWS 64           // rows per block (4 waves x 16 rows)
#define TC 32             // codes per LDS tile
#define NT (KC / TC)      // 32 tiles
#define NQ (NT / 4)       // 8 quad-phases
#define BCH 33            // chunk stride (16B chunks) for bank-conflict-free B
#define TILE_SH (16 * BCH * 8)  // 4224 shorts per tile slot

typedef short short8 __attribute__((ext_vector_type(8)));
typedef short short4v __attribute__((ext_vector_type(4)));
typedef float f32x4 __attribute__((ext_vector_type(4)));

__device__ __forceinline__ unsigned short f2bf(float x) {
  unsigned int u = __float_as_uint(x);
  unsigned int r = (u + 0x7fffu + ((u >> 16) & 1u)) >> 16;
  return (unsigned short)r;
}
__device__ __forceinline__ float bf2f(unsigned short h) {
  return __uint_as_float((unsigned int)h << 16);
}

// split two float4 (8 floats) into hi/lo bf16 short8
__device__ __forceinline__ void split8(const float4 a, const float4 b,
                                       short8* hi, short8* lo) {
  float f[8] = {a.x, a.y, a.z, a.w, b.x, b.y, b.z, b.w};
#pragma unroll
  for (int i = 0; i < 8; ++i) {
    unsigned short h = f2bf(f[i]);
    (*hi)[i] = (short)h;
    (*lo)[i] = (short)f2bf(f[i] - bf2f(h));
  }
}

// Precompute: exact fp32 code norms, split-bf16 codebook
// bsplit[k][128] = [e_hi(64) | e_lo(64)], zero hist/loss.
__global__ __launch_bounds__(256) void vq_prep(
    const float* __restrict__ cb, unsigned short* __restrict__ bsplit,
    float* __restrict__ cbn, unsigned int* __restrict__ hist,
    float* __restrict__ loss_acc) {
  const int k = blockIdx.x * 256 + threadIdx.x;  // 0..1023
  const float4* e = (const float4*)(cb + (size_t)k * D);
  unsigned short* bp = bsplit + (size_t)k * 128;
  float s0 = 0.f, s1 = 0.f, s2 = 0.f, s3 = 0.f;
#pragma unroll
  for (int i = 0; i < 16; ++i) {
    float4 v = e[i];
    s0 = fmaf(v.x, v.x, s0);
    s1 = fmaf(v.y, v.y, s1);
    s2 = fmaf(v.z, v.z, s2);
    s3 = fmaf(v.w, v.w, s3);
    unsigned short h0 = f2bf(v.x), h1 = f2bf(v.y), h2 = f2bf(v.z), h3 = f2bf(v.w);
    short4v hv = {(short)h0, (short)h1, (short)h2, (short)h3};
    short4v lv = {(short)f2bf(v.x - bf2f(h0)), (short)f2bf(v.y - bf2f(h1)),
                  (short)f2bf(v.z - bf2f(h2)), (short)f2bf(v.w - bf2f(h3))};
    *(short4v*)(bp + i * 4) = hv;
    *(short4v*)(bp + 64 + i * 4) = lv;
  }
  cbn[k] = (s0 + s1) + (s2 + s3);
  hist[k] = 0u;
  if (k == 0) loss_acc[0] = 0.f;
}

__global__ __launch_bounds__(256, 2) void vq_main(
    const float* __restrict__ z, const unsigned short* __restrict__ bsplit,
    const float* __restrict__ cbn, const float* __restrict__ cb,
    float* __restrict__ out_q, float* __restrict__ out_idx,
    unsigned int* __restrict__ hist, float* __restrict__ loss_acc) {
  // B double buffer of tile QUADS: [buf][tile-in-quad][16 chunk-rows x 33].
  __shared__ __align__(16) unsigned short Bsh[2][4][TILE_SH];
  __shared__ float scbn[KC];
  __shared__ int skf[ROWS];
  __shared__ float swav[4];
  __shared__ unsigned int lhist[KC];

  const int tid = threadIdx.x;
  const int lane = tid & 63;
  const int wav = tid >> 6;
  const int quad = lane >> 4;
  const int col = lane & 15;
  const int rowbase = blockIdx.x * ROWS;

  // ---- prologue
  // Direct A-fragment z loads: lane owns row wav*16+col,
  // k in {quad*8..+8, 32+quad*8..+8} -> 4 float4 (issue first, longest dep).
  const int arow = rowbase + wav * 16 + col;
  const float4* zr = (const float4*)(z + (size_t)arow * D);
  const float4 f0 = zr[quad * 2];
  const float4 f1 = zr[quad * 2 + 1];
  const float4 f2 = zr[8 + quad * 2];
  const float4 f3 = zr[8 + quad * 2 + 1];

  // cbn -> LDS, zero lhist
  *(float4*)&scbn[tid * 4] = *(const float4*)&cbn[tid * 4];
#pragma unroll
  for (int j = 0; j < KC / 256; ++j) lhist[tid + 256 * j] = 0u;

  // stage quad 0: per tile, thread t moves global chunks t and t+256.
  // chunk c: code k=c>>4, plane-chunk jj=c&15; LDS slot = jj*BCH + k.
  const int cslot = (tid & 15) * BCH + (tid >> 4);  // slot for chunk tid
#pragma unroll
  for (int T = 0; T < 4; ++T) {
    const size_t off =
        (size_t)(T * TC + (tid >> 4)) * 128 + (size_t)(tid & 15) * 8;
    short8 q0 = *(const short8*)(bsplit + off);
    short8 q1 = *(const short8*)(bsplit + off + 2048);  // +16 codes
    *(short8*)&Bsh[0][T][cslot * 8] = q0;
    *(short8*)&Bsh[0][T][(cslot + 16) * 8] = q1;
  }

  // in-register split-bf16 A-frags
  short8 a0, a1, a2, a3;
  split8(f0, f1, &a0, &a2);  // z_hi / z_lo, k = quad*8 .. +8
  split8(f2, f3, &a1, &a3);  // z_hi / z_lo, k = 32+quad*8 .. +8

  // row norm: per-lane partial (16 elems), quads of same col cover the row.
  float nrm = ((f0.x * f0.x + f0.y * f0.y) + (f0.z * f0.z + f0.w * f0.w)) +
              ((f1.x * f1.x + f1.y * f1.y) + (f1.z * f1.z + f1.w * f1.w)) +
              ((f2.x * f2.x + f2.y * f2.y) + (f2.z * f2.z + f2.w * f2.w)) +
              ((f3.x * f3.x + f3.y * f3.y) + (f3.z * f3.z + f3.w * f3.w));
  nrm += __shfl_xor(nrm, 16, 64);
  nrm += __shfl_xor(nrm, 32, 64);
  // Norm is row-constant so it cancels in all same-row comparisons.
  float rzv[4];
#pragma unroll
  for (int r = 0; r < 4; ++r) rzv[r] = __shfl(nrm, quad * 4 + r, 64);

  __syncthreads();  // covers quad-0 ds_writes + scbn + lhist

  // TWO independent top-2 states (split fold chains): A <- tiles {0,1} of
  // each quad, B <- tiles {2,3}. Merged in-register after the loop.
  float b1dA[4], b2dA[4], b1dB[4], b2dB[4];
  int b1kA[4], b2kA[4], b1kB[4], b2kB[4];
#pragma unroll
  for (int i = 0; i < 4; ++i) {
    b1dA[i] = 3.4e38f; b2dA[i] = 3.4e38f;
    b1kA[i] = 0x7fffffff; b2kA[i] = 0x7fffffff;
    b1dB[i] = 3.4e38f; b2dB[i] = 3.4e38f;
    b1kB[i] = 0x7fffffff; b2kB[i] = 0x7fffffff;
  }

  // top-2 fold step (strict < + ascending scan keeps lowest k) -- R13 logic
  auto fold = [&](float (&B1D)[4], int (&B1K)[4], float (&B2D)[4],
                  int (&B2K)[4], float d, int k, int reg) {
    bool w1 = d < B1D[reg];
    bool w2 = d < B2D[reg];
    B2D[reg] = w1 ? B1D[reg] : (w2 ? d : B2D[reg]);
    B2K[reg] = w1 ? B1K[reg] : (w2 ? k : B2K[reg]);
    B1D[reg] = w1 ? d : B1D[reg];
    B1K[reg] = w1 ? k : B1K[reg];
  };

  // ---- K-loop: 8 quad-phases of 4x32 codes, double-buffered LDS quads
  for (int p = 0; p < NQ; ++p) {
    // stage next quad: global -> regs (lands during this phase's compute)
    short8 s0, s1, s2, s3, s4, s5, s6, s7;
    if (p + 1 < NQ) {
      const size_t base = (size_t)((p + 1) * 4) * TC;
      const size_t o0 = (base + (tid >> 4)) * 128 + (size_t)(tid & 15) * 8;
      s0 = *(const short8*)(bsplit + o0);
      s1 = *(const short8*)(bsplit + o0 + 2048);
      s2 = *(const short8*)(bsplit + o0 + 4096);   // tile 1
      s3 = *(const short8*)(bsplit + o0 + 6144);
      s4 = *(const short8*)(bsplit + o0 + 8192);   // tile 2
      s5 = *(const short8*)(bsplit + o0 + 10240);
      s6 = *(const short8*)(bsplit + o0 + 12288);  // tile 3
      s7 = *(const short8*)(bsplit + o0 + 14336);
    }
#pragma unroll
    for (int T = 0; T < 4; ++T) {
      const int kb = (p * 4 + T) * TC;
      const unsigned short* bcur = &Bsh[p & 1][T][0];
      const float enA = scbn[kb + col];
      const float enB = scbn[kb + 16 + col];
      // B-frags: chain A = code col, chain B = code col+16.
      // frag i lives at chunk-row i*4+quad, slot = row*BCH + code.
      const short8 bA0 = *(const short8*)(bcur + ((0 + quad) * BCH + col) * 8);
      const short8 bA1 = *(const short8*)(bcur + ((4 + quad) * BCH + col) * 8);
      const short8 bA2 = *(const short8*)(bcur + ((8 + quad) * BCH + col) * 8);
      const short8 bA3 = *(const short8*)(bcur + ((12 + quad) * BCH + col) * 8);
      const short8 bB0 =
          *(const short8*)(bcur + ((0 + quad) * BCH + col + 16) * 8);
      const short8 bB1 =
          *(const short8*)(bcur + ((4 + quad) * BCH + col + 16) * 8);
      const short8 bB2 =
          *(const short8*)(bcur + ((8 + quad) * BCH + col + 16) * 8);
      const short8 bB3 =
          *(const short8*)(bcur + ((12 + quad) * BCH + col + 16) * 8);

      f32x4 accA = {0.f, 0.f, 0.f, 0.f}, accB = {0.f, 0.f, 0.f, 0.f};
      // 3-term split: hi.hi + lo.hi + hi.lo ; two independent chains per tile
      accA = __builtin_amdgcn_mfma_f32_16x16x32_bf16(a0, bA0, accA, 0, 0, 0);
      accB = __builtin_amdgcn_mfma_f32_16x16x32_bf16(a0, bB0, accB, 0, 0, 0);
      accA = __builtin_amdgcn_mfma_f32_16x16x32_bf16(a1, bA1, accA, 0, 0, 0);
      accB = __builtin_amdgcn_mfma_f32_16x16x32_bf16(a1, bB1, accB, 0, 0, 0);
      accA = __builtin_amdgcn_mfma_f32_16x16x32_bf16(a2, bA0, accA, 0, 0, 0);
      accB = __builtin_amdgcn_mfma_f32_16x16x32_bf16(a2, bB0, accB, 0, 0, 0);
      accA = __builtin_amdgcn_mfma_f32_16x16x32_bf16(a3, bA1, accA, 0, 0, 0);
      accB = __builtin_amdgcn_mfma_f32_16x16x32_bf16(a3, bB1, accB, 0, 0, 0);
      accA = __builtin_amdgcn_mfma_f32_16x16x32_bf16(a0, bA2, accA, 0, 0, 0);
      accB = __builtin_amdgcn_mfma_f32_16x16x32_bf16(a0, bB2, accB, 0, 0, 0);
      accA = __builtin_amdgcn_mfma_f32_16x16x32_bf16(a1, bA3, accA, 0, 0, 0);
      accB = __builtin_amdgcn_mfma_f32_16x16x32_bf16(a1, bB3, accB, 0, 0, 0);

      // fold: tiles {0,1} -> state A, tiles {2,3} -> state B (T is a
      // compile-time constant under the unroll -> static selection)
#pragma unroll
      for (int reg = 0; reg < 4; ++reg) {
        if (T < 2) {
          fold(b1dA, b1kA, b2dA, b2kA, fmaf(-2.0f, accA[reg], rzv[reg] + enA),
               kb + col, reg);
          fold(b1dA, b1kA, b2dA, b2kA, fmaf(-2.0f, accB[reg], rzv[reg] + enB),
               kb + 16 + col, reg);
        } else {
          fold(b1dB, b1kB, b2dB, b2kB, fmaf(-2.0f, accA[reg], rzv[reg] + enA),
               kb + col, reg);
          fold(b1dB, b1kB, b2dB, b2kB, fmaf(-2.0f, accB[reg], rzv[reg] + enB),
               kb + 16 + col, reg);
        }
      }
    }

    // commit staged regs to the other quad buffer, then barrier
    if (p + 1 < NQ) {
      unsigned short* bn0 = &Bsh[(p + 1) & 1][0][0];
      unsigned short* bn1 = &Bsh[(p + 1) & 1][1][0];
      unsigned short* bn2 = &Bsh[(p + 1) & 1][2][0];
      unsigned short* bn3 = &Bsh[(p + 1) & 1][3][0];
      *(short8*)&bn0[cslot * 8] = s0;
      *(short8*)&bn0[(cslot + 16) * 8] = s1;
      *(short8*)&bn1[cslot * 8] = s2;
      *(short8*)&bn1[(cslot + 16) * 8] = s3;
      *(short8*)&bn2[cslot * 8] = s4;
      *(short8*)&bn2[(cslot + 16) * 8] = s5;
      *(short8*)&bn3[cslot * 8] = s6;
      *(short8*)&bn3[(cslot + 16) * 8] = s7;
    }
    __syncthreads();
  }

  // ---- merge state B into state A (in-register, per lane; same
  // lexicographic merge as the verified cross-parity merge)
#pragma unroll
  for (int reg = 0; reg < 4; ++reg) {
    float od1 = b1dB[reg];
    int ok1 = b1kB[reg];
    float od2 = b2dB[reg];
    int ok2 = b2kB[reg];
    bool fo = (od1 < b1dA[reg]) || (od1 == b1dA[reg] && ok1 < b1kA[reg]);
    float w1 = fo ? od1 : b1dA[reg];
    int wk1 = fo ? ok1 : b1kA[reg];
    float l1 = fo ? b1dA[reg] : od1;
    int lk1 = fo ? b1kA[reg] : ok1;
    bool so = (od2 < b2dA[reg]) || (od2 == b2dA[reg] && ok2 < b2kA[reg]);
    float m2 = so ? od2 : b2dA[reg];
    int mk2 = so ? ok2 : b2kA[reg];
    bool lw = (l1 < m2) || (l1 == m2 && lk1 < mk2);
    b1dA[reg] = w1;
    b1kA[reg] = wk1;
    b2dA[reg] = lw ? l1 : m2;
    b2kA[reg] = lw ? lk1 : mk2;
  }

  // ---- cross-lane top-2 butterfly over the 16 col-classes (within quad group)
#pragma unroll
  for (int m = 1; m < 16; m <<= 1) {
#pragma unroll
    for (int reg = 0; reg < 4; ++reg) {
      float od1 = __shfl_xor(b1dA[reg], m, 64);
      int ok1 = __shfl_xor(b1kA[reg], m, 64);
      float od2 = __shfl_xor(b2dA[reg], m, 64);
      int ok2 = __shfl_xor(b2kA[reg], m, 64);
      bool fo = (od1 < b1dA[reg]) || (od1 == b1dA[reg] && ok1 < b1kA[reg]);
      float w1 = fo ? od1 : b1dA[reg];
      int wk1 = fo ? ok1 : b1kA[reg];
      float l1 = fo ? b1dA[reg] : od1;
      int lk1 = fo ? b1kA[reg] : ok1;
      bool so = (od2 < b2dA[reg]) || (od2 == b2dA[reg] && ok2 < b2kA[reg]);
      float m2 = so ? od2 : b2dA[reg];
      int mk2 = so ? ok2 : b2kA[reg];
      bool lw = (l1 < m2) || (l1 == m2 && lk1 < mk2);
      b1dA[reg] = w1;
      b1kA[reg] = wk1;
      b2dA[reg] = lw ? l1 : m2;
      b2kA[reg] = lw ? lk1 : mk2;
    }
  }

  // writer lanes: col<4 handles row = wav*16 + quad*4 + col (using reg=col)
  if (col < 4) {
    const int row = wav * 16 + quad * 4 + col;
    float bd1 = b1dA[col], bd2 = b2dA[col];
    int bk1 = b1kA[col], bk2 = b2kA[col];
    if (bd2 - bd1 < 1e-5f) {
      // exact fp32 recompute (R3 arithmetic) of the top-2 candidates
      const int grow = rowbase + row;
      const float4* zp = (const float4*)(z + (size_t)grow * D);
      float s0 = 0.f, s1 = 0.f, s2 = 0.f, s3 = 0.f;
#pragma unroll
      for (int i = 0; i < 16; ++i) {
        float4 v = zp[i];
        s0 = fmaf(v.x, v.x, s0);
        s1 = fmaf(v.y, v.y, s1);
        s2 = fmaf(v.z, v.z, s2);
        s3 = fmaf(v.w, v.w, s3);
      }
      const float rzx = (s0 + s1) + (s2 + s3);
      float dx[2];
      int kk[2] = {bk1, bk2};
#pragma unroll
      for (int c = 0; c < 2; ++c) {
        const float4* e4 = (const float4*)(cb + (size_t)kk[c] * D);
        float d0 = 0.f, d1 = 0.f, d2 = 0.f, d3 = 0.f;
#pragma unroll
        for (int i = 0; i < 16; ++i) {
          float4 v = e4[i];
          float4 zv = zp[i];
          d0 = fmaf(zv.x, v.x, d0);
          d1 = fmaf(zv.y, v.y, d1);
          d2 = fmaf(zv.z, v.z, d2);
          d3 = fmaf(zv.w, v.w, d3);
        }
        float dot = (d0 + d1) + (d2 + d3);
        dx[c] = (rzx + scbn[kk[c]]) - 2.0f * dot;
      }
      if ((dx[1] < dx[0]) || (dx[1] == dx[0] && bk2 < bk1)) bk1 = bk2;
    }
    skf[row] = bk1;
    out_idx[rowbase + row] = (float)bk1;
    atomicAdd(&lhist[bk1], 1u);
  }
  __syncthreads();

  // ---- flush per-block histogram: one global atomic per distinct code
#pragma unroll
  for (int j = 0; j < KC / 256; ++j) {
    unsigned int c = lhist[tid + 256 * j];
    if (c) atomicAdd(&hist[tid + 256 * j], c);
  }

  // ---- epilogue: quantized write (exact fp32 codebook rows) + loss partial
  float lsum = 0.f;
#pragma unroll
  for (int it = 0; it < 4; ++it) {
    int f4 = it * 256 + tid;
    int r = f4 >> 4;
    int c4 = (f4 & 15) * 4;
    int bk = skf[r];
    const float4 q = *(const float4*)(cb + (size_t)bk * D + c4);
    const int grow = rowbase + r;
    const float4 zv = *(const float4*)(z + (size_t)grow * D + c4);
    *(float4*)(out_q + (size_t)grow * D + c4) = q;
    float ax = q.x - zv.x, ay = q.y - zv.y, az = q.z - zv.z, aw = q.w - zv.w;
    lsum += ax * ax + ay * ay + az * az + aw * aw;
  }
#pragma unroll
  for (int off = 32; off > 0; off >>= 1) lsum += __shfl_down(lsum, off, 64);
  if (lane == 0) swav[wav] = lsum;
  __syncthreads();
  if (tid == 0) {
    atomicAdd(loss_acc, (swav[0] + swav[1]) + (swav[2] + swav[3]));
  }
}

__global__ __launch_bounds__(1024) void vq_final(
    const unsigned int* __restrict__ hist, const float* __restrict__ loss_acc,
    float* __restrict__ out_loss, float* __restrict__ out_perp, float inv_n,
    float inv_nd) {
  __shared__ float part[16];
  const int t = threadIdx.x;
  const int lane = t & 63;
  const int wav = t >> 6;
  float p = (float)hist[t] * inv_n;
  float v = p * logf(p + 1e-10f);
#pragma unroll
  for (int off = 32; off > 0; off >>= 1) v += __shfl_down(v, off, 64);
  if (lane == 0) part[wav] = v;
  __syncthreads();
  if (t == 0) {
    float s = 0.f;
#pragma unroll
    for (int j = 0; j < 16; ++j) s += part[j];
    *out_perp = expf(-s);
    // q_latent + 0.25*e_latent, both numerically mean((q-z)^2)
    *out_loss = 1.25f * loss_acc[0] * inv_nd;
  }
}

extern "C" void kernel_launch(void* const* d_in, const int* in_sizes, int n_in,
                              void* d_out, int out_size, void* d_ws,
                              size_t ws_size, hipStream_t stream) {
  (void)n_in;
  (void)out_size;
  (void)ws_size;
  const float* z = (const float*)d_in[0];
  const float* cb = (const float*)d_in[1];
  const int N = in_sizes[0] / D;  // 32768

  // Output layout (flat float32, reference return order):
  float* out_q = (float*)d_out;                     // N*D
  float* out_loss = (float*)d_out + (size_t)N * D;  // 1
  float* out_idx = out_loss + 1;                    // N
  float* out_perp = out_idx + N;                    // 1

  // Workspace (floats): hist[1024] @0, loss_acc @1024, cbn[1024] @1040,
  // bsplit (short[1024*128]) @ float-idx 2064 (byte 8256, 16B-aligned).
  unsigned int* hist = (unsigned int*)d_ws;
  float* loss_acc = (float*)d_ws + 1024;
  float* cbn = (float*)d_ws + 1040;
  unsigned short* bsplit = (unsigned short*)((float*)d_ws + 2064);

  vq_prep<<<dim3(KC / 256), dim3(256), 0, stream>>>(cb, bsplit, cbn, hist,
                                                    loss_acc);
  vq_main<<<dim3(N / ROWS), dim3(256), 0, stream>>>(z, bsplit, cbn, cb, out_q,
                                                    out_idx, hist, loss_acc);
  vq_final<<<dim3(1), dim3(1024), 0, stream>>>(
      hist, loss_acc, out_loss, out_perp, 1.0f / (float)N,
      1.0f / ((float)N * (float)D));
}

// Round 10
// 97.740 us; speedup vs baseline: 1.3636x; 1.0117x over previous
//
#include <hip/hip_runtime.h>
#include <math.h>

// VQ-VAE vector quantizer for MI355X (gfx950).
// z: [32768, 64] fp32, codebook: [1024, 64] fp32.
// Outputs (flat float32, concatenated): quantized_st [32768*64], vq_loss [1],
// indices [32768] (as float), perplexity [1].
//
// R20 (FINAL): revert to R13, the best-measured variant (97.6us). Session
// ledger: R13 97.6 / R12 98.1 / R19 98.9 / R15 99.1 / R18 101.6; structural
// departures worse (R16 fused 108.7, R17 global-gather 133.3, grid-1024
// parity splits 144.5/219.8 -- VGPR-cap spill pathology). Counter-verified
// nulls: HBM 3.9% peak, LDS-BW (R18), conflicts ~4cy/read, occupancy ceiling
// (R13: grid supplies only 2 blocks/CU), prefetch depth (R15), barrier
// removal (R17), phase count <16 (R19), fold ILP (R19). Total decomposes:
// ~44us harness 256MiB ws-poison fill (83% HBM peak, irreducible) + ~33us
// vq_main (latency-bound plateau at 2 waves/SIMD) + ~20us prep/final/gaps.
// Structure: 16 pair-phases, double-buffered LDS tile pairs (BCH-33 layout),
// LDS-diet prologue (direct per-lane z loads, in-register split-bf16, shfl
// row norms -- norm cancels in comparisons), per-lane exact top-2 + shuffle
// butterfly, margin recheck in exact fp32, lhist + separate vq_final.
// Numerics: 3-term split-bf16 + exact fp32 recheck (margin 1e-5).

#define D 64
#define KC 1024
#define ROWS 64           // rows per block (4 waves x 16 rows)
#define TC 32             // codes per LDS tile
#define NT (KC / TC)      // 32 tiles
#define NP (NT / 2)       // 16 pair-phases
#define BCH 33            // chunk stride (16B chunks) for bank-conflict-free B
#define TILE_SH (16 * BCH * 8)  // 4224 shorts per tile slot

typedef short short8 __attribute__((ext_vector_type(8)));
typedef short short4v __attribute__((ext_vector_type(4)));
typedef float f32x4 __attribute__((ext_vector_type(4)));

__device__ __forceinline__ unsigned short f2bf(float x) {
  unsigned int u = __float_as_uint(x);
  unsigned int r = (u + 0x7fffu + ((u >> 16) & 1u)) >> 16;
  return (unsigned short)r;
}
__device__ __forceinline__ float bf2f(unsigned short h) {
  return __uint_as_float((unsigned int)h << 16);
}

// split two float4 (8 floats) into hi/lo bf16 short8
__device__ __forceinline__ void split8(const float4 a, const float4 b,
                                       short8* hi, short8* lo) {
  float f[8] = {a.x, a.y, a.z, a.w, b.x, b.y, b.z, b.w};
#pragma unroll
  for (int i = 0; i < 8; ++i) {
    unsigned short h = f2bf(f[i]);
    (*hi)[i] = (short)h;
    (*lo)[i] = (short)f2bf(f[i] - bf2f(h));
  }
}

// Precompute: exact fp32 code norms, split-bf16 codebook
// bsplit[k][128] = [e_hi(64) | e_lo(64)], zero hist/loss.
__global__ __launch_bounds__(256) void vq_prep(
    const float* __restrict__ cb, unsigned short* __restrict__ bsplit,
    float* __restrict__ cbn, unsigned int* __restrict__ hist,
    float* __restrict__ loss_acc) {
  const int k = blockIdx.x * 256 + threadIdx.x;  // 0..1023
  const float4* e = (const float4*)(cb + (size_t)k * D);
  unsigned short* bp = bsplit + (size_t)k * 128;
  float s0 = 0.f, s1 = 0.f, s2 = 0.f, s3 = 0.f;
#pragma unroll
  for (int i = 0; i < 16; ++i) {
    float4 v = e[i];
    s0 = fmaf(v.x, v.x, s0);
    s1 = fmaf(v.y, v.y, s1);
    s2 = fmaf(v.z, v.z, s2);
    s3 = fmaf(v.w, v.w, s3);
    unsigned short h0 = f2bf(v.x), h1 = f2bf(v.y), h2 = f2bf(v.z), h3 = f2bf(v.w);
    short4v hv = {(short)h0, (short)h1, (short)h2, (short)h3};
    short4v lv = {(short)f2bf(v.x - bf2f(h0)), (short)f2bf(v.y - bf2f(h1)),
                  (short)f2bf(v.z - bf2f(h2)), (short)f2bf(v.w - bf2f(h3))};
    *(short4v*)(bp + i * 4) = hv;
    *(short4v*)(bp + 64 + i * 4) = lv;
  }
  cbn[k] = (s0 + s1) + (s2 + s3);
  hist[k] = 0u;
  if (k == 0) loss_acc[0] = 0.f;
}

__global__ __launch_bounds__(256, 3) void vq_main(
    const float* __restrict__ z, const unsigned short* __restrict__ bsplit,
    const float* __restrict__ cbn, const float* __restrict__ cb,
    float* __restrict__ out_q, float* __restrict__ out_idx,
    unsigned int* __restrict__ hist, float* __restrict__ loss_acc) {
  // B double buffer of tile PAIRS: [buf][tile-in-pair][16 chunk-rows x 33].
  __shared__ __align__(16) unsigned short Bsh[2][2][TILE_SH];
  __shared__ float scbn[KC];
  __shared__ int skf[ROWS];
  __shared__ float swav[4];
  __shared__ unsigned int lhist[KC];

  const int tid = threadIdx.x;
  const int lane = tid & 63;
  const int wav = tid >> 6;
  const int quad = lane >> 4;
  const int col = lane & 15;
  const int rowbase = blockIdx.x * ROWS;

  // ---- prologue
  // Direct A-fragment z loads: lane owns row wav*16+col,
  // k in {quad*8..+8, 32+quad*8..+8} -> 4 float4 (issue first, longest dep).
  const int arow = rowbase + wav * 16 + col;
  const float4* zr = (const float4*)(z + (size_t)arow * D);
  const float4 f0 = zr[quad * 2];
  const float4 f1 = zr[quad * 2 + 1];
  const float4 f2 = zr[8 + quad * 2];
  const float4 f3 = zr[8 + quad * 2 + 1];

  // cbn -> LDS, zero lhist
  *(float4*)&scbn[tid * 4] = *(const float4*)&cbn[tid * 4];
#pragma unroll
  for (int j = 0; j < KC / 256; ++j) lhist[tid + 256 * j] = 0u;

  // stage pair 0: per tile, thread t moves global chunks t and t+256.
  // chunk g: code k=g>>4, plane-chunk jj=g&15; LDS slot = jj*BCH + k.
  const int cslot = (tid & 15) * BCH + (tid >> 4);  // slot for chunk tid
#pragma unroll
  for (int T = 0; T < 2; ++T) {
    const size_t off =
        (size_t)(T * TC + (tid >> 4)) * 128 + (size_t)(tid & 15) * 8;
    short8 s0 = *(const short8*)(bsplit + off);
    short8 s1 = *(const short8*)(bsplit + off + 2048);  // +16 codes
    *(short8*)&Bsh[0][T][cslot * 8] = s0;
    *(short8*)&Bsh[0][T][(cslot + 16) * 8] = s1;
  }

  // in-register split-bf16 A-frags
  short8 a0, a1, a2, a3;
  split8(f0, f1, &a0, &a2);  // z_hi / z_lo, k = quad*8 .. +8
  split8(f2, f3, &a1, &a3);  // z_hi / z_lo, k = 32+quad*8 .. +8

  // row norm: per-lane partial (16 elems), quads of same col cover the row.
  float nrm = ((f0.x * f0.x + f0.y * f0.y) + (f0.z * f0.z + f0.w * f0.w)) +
              ((f1.x * f1.x + f1.y * f1.y) + (f1.z * f1.z + f1.w * f1.w)) +
              ((f2.x * f2.x + f2.y * f2.y) + (f2.z * f2.z + f2.w * f2.w)) +
              ((f3.x * f3.x + f3.y * f3.y) + (f3.z * f3.z + f3.w * f3.w));
  nrm += __shfl_xor(nrm, 16, 64);
  nrm += __shfl_xor(nrm, 32, 64);
  // acc[reg] corresponds to output row quad*4+reg; its norm lives at lane
  // col'=quad*4+reg (any quad). Norm is row-constant so precision only
  // shifts all distances of a row equally -> selection unaffected.
  float rzv[4];
#pragma unroll
  for (int r = 0; r < 4; ++r) rzv[r] = __shfl(nrm, quad * 4 + r, 64);

  __syncthreads();  // covers pair-0 ds_writes + scbn + lhist

  // per-lane exact top-2 over this lane's code class (col mod 16)
  float b1d[4], b2d[4];
  int b1k[4], b2k[4];
#pragma unroll
  for (int i = 0; i < 4; ++i) {
    b1d[i] = 3.4e38f; b2d[i] = 3.4e38f;
    b1k[i] = 0x7fffffff; b2k[i] = 0x7fffffff;
  }

  // ---- K-loop: 16 pair-phases of 2x32 codes, double-buffered LDS pairs
  for (int p = 0; p < NP; ++p) {
    // stage next pair: global -> regs (lands during this phase's compute)
    short8 st00, st01, st10, st11;
    if (p + 1 < NP) {
      const size_t base = (size_t)((p + 1) * 2) * TC;
      const size_t o0 = (base + (tid >> 4)) * 128 + (size_t)(tid & 15) * 8;
      st00 = *(const short8*)(bsplit + o0);
      st01 = *(const short8*)(bsplit + o0 + 2048);
      st10 = *(const short8*)(bsplit + o0 + 4096);  // +32 codes (tile 1)
      st11 = *(const short8*)(bsplit + o0 + 6144);
    }
#pragma unroll
    for (int T = 0; T < 2; ++T) {
      const int kb = (p * 2 + T) * TC;
      const unsigned short* bcur = &Bsh[p & 1][T][0];
      const float enA = scbn[kb + col];
      const float enB = scbn[kb + 16 + col];
      // B-frags: chain A = code col, chain B = code col+16.
      // frag i lives at chunk-row i*4+quad, slot = row*BCH + code.
      const short8 bA0 = *(const short8*)(bcur + ((0 + quad) * BCH + col) * 8);
      const short8 bA1 = *(const short8*)(bcur + ((4 + quad) * BCH + col) * 8);
      const short8 bA2 = *(const short8*)(bcur + ((8 + quad) * BCH + col) * 8);
      const short8 bA3 = *(const short8*)(bcur + ((12 + quad) * BCH + col) * 8);
      const short8 bB0 =
          *(const short8*)(bcur + ((0 + quad) * BCH + col + 16) * 8);
      const short8 bB1 =
          *(const short8*)(bcur + ((4 + quad) * BCH + col + 16) * 8);
      const short8 bB2 =
          *(const short8*)(bcur + ((8 + quad) * BCH + col + 16) * 8);
      const short8 bB3 =
          *(const short8*)(bcur + ((12 + quad) * BCH + col + 16) * 8);

      f32x4 accA = {0.f, 0.f, 0.f, 0.f}, accB = {0.f, 0.f, 0.f, 0.f};
      // 3-term split: hi.hi + lo.hi + hi.lo ; two independent chains per tile
      accA = __builtin_amdgcn_mfma_f32_16x16x32_bf16(a0, bA0, accA, 0, 0, 0);
      accB = __builtin_amdgcn_mfma_f32_16x16x32_bf16(a0, bB0, accB, 0, 0, 0);
      accA = __builtin_amdgcn_mfma_f32_16x16x32_bf16(a1, bA1, accA, 0, 0, 0);
      accB = __builtin_amdgcn_mfma_f32_16x16x32_bf16(a1, bB1, accB, 0, 0, 0);
      accA = __builtin_amdgcn_mfma_f32_16x16x32_bf16(a2, bA0, accA, 0, 0, 0);
      accB = __builtin_amdgcn_mfma_f32_16x16x32_bf16(a2, bB0, accB, 0, 0, 0);
      accA = __builtin_amdgcn_mfma_f32_16x16x32_bf16(a3, bA1, accA, 0, 0, 0);
      accB = __builtin_amdgcn_mfma_f32_16x16x32_bf16(a3, bB1, accB, 0, 0, 0);
      accA = __builtin_amdgcn_mfma_f32_16x16x32_bf16(a0, bA2, accA, 0, 0, 0);
      accB = __builtin_amdgcn_mfma_f32_16x16x32_bf16(a0, bB2, accB, 0, 0, 0);
      accA = __builtin_amdgcn_mfma_f32_16x16x32_bf16(a1, bA3, accA, 0, 0, 0);
      accB = __builtin_amdgcn_mfma_f32_16x16x32_bf16(a1, bB3, accB, 0, 0, 0);

      // fold with exact per-lane top-2; strict < + ascending scan keeps lowest k
#pragma unroll
      for (int reg = 0; reg < 4; ++reg) {
        {
          float d = fmaf(-2.0f, accA[reg], rzv[reg] + enA);
          int k = kb + col;
          bool w1 = d < b1d[reg];
          bool w2 = d < b2d[reg];
          b2d[reg] = w1 ? b1d[reg] : (w2 ? d : b2d[reg]);
          b2k[reg] = w1 ? b1k[reg] : (w2 ? k : b2k[reg]);
          b1d[reg] = w1 ? d : b1d[reg];
          b1k[reg] = w1 ? k : b1k[reg];
        }
        {
          float d = fmaf(-2.0f, accB[reg], rzv[reg] + enB);
          int k = kb + 16 + col;
          bool w1 = d < b1d[reg];
          bool w2 = d < b2d[reg];
          b2d[reg] = w1 ? b1d[reg] : (w2 ? d : b2d[reg]);
          b2k[reg] = w1 ? b1k[reg] : (w2 ? k : b2k[reg]);
          b1d[reg] = w1 ? d : b1d[reg];
          b1k[reg] = w1 ? k : b1k[reg];
        }
      }
    }

    // commit staged regs to the other pair buffer, then barrier
    if (p + 1 < NP) {
      unsigned short* bn0 = &Bsh[(p + 1) & 1][0][0];
      unsigned short* bn1 = &Bsh[(p + 1) & 1][1][0];
      *(short8*)&bn0[cslot * 8] = st00;
      *(short8*)&bn0[(cslot + 16) * 8] = st01;
      *(short8*)&bn1[cslot * 8] = st10;
      *(short8*)&bn1[(cslot + 16) * 8] = st11;
    }
    __syncthreads();
  }

  // ---- cross-lane top-2 butterfly over the 16 col-classes (within quad group)
#pragma unroll
  for (int m = 1; m < 16; m <<= 1) {
#pragma unroll
    for (int reg = 0; reg < 4; ++reg) {
      float od1 = __shfl_xor(b1d[reg], m, 64);
      int ok1 = __shfl_xor(b1k[reg], m, 64);
      float od2 = __shfl_xor(b2d[reg], m, 64);
      int ok2 = __shfl_xor(b2k[reg], m, 64);
      bool fo = (od1 < b1d[reg]) || (od1 == b1d[reg] && ok1 < b1k[reg]);
      float w1 = fo ? od1 : b1d[reg];
      int wk1 = fo ? ok1 : b1k[reg];
      float l1 = fo ? b1d[reg] : od1;
      int lk1 = fo ? b1k[reg] : ok1;
      bool so = (od2 < b2d[reg]) || (od2 == b2d[reg] && ok2 < b2k[reg]);
      float m2 = so ? od2 : b2d[reg];
      int mk2 = so ? ok2 : b2k[reg];
      bool lw = (l1 < m2) || (l1 == m2 && lk1 < mk2);
      b1d[reg] = w1;
      b1k[reg] = wk1;
      b2d[reg] = lw ? l1 : m2;
      b2k[reg] = lw ? lk1 : mk2;
    }
  }

  // writer lanes: col<4 handles row = wav*16 + quad*4 + col (using reg=col)
  if (col < 4) {
    const int row = wav * 16 + quad * 4 + col;
    float bd1 = b1d[col], bd2 = b2d[col];
    int bk1 = b1k[col], bk2 = b2k[col];
    if (bd2 - bd1 < 1e-5f) {
      // exact fp32 recompute (R3 arithmetic) of the top-2 candidates
      const int grow = rowbase + row;
      const float4* zp = (const float4*)(z + (size_t)grow * D);
      float s0 = 0.f, s1 = 0.f, s2 = 0.f, s3 = 0.f;
#pragma unroll
      for (int i = 0; i < 16; ++i) {
        float4 v = zp[i];
        s0 = fmaf(v.x, v.x, s0);
        s1 = fmaf(v.y, v.y, s1);
        s2 = fmaf(v.z, v.z, s2);
        s3 = fmaf(v.w, v.w, s3);
      }
      const float rzx = (s0 + s1) + (s2 + s3);
      float dx[2];
      int kk[2] = {bk1, bk2};
#pragma unroll
      for (int c = 0; c < 2; ++c) {
        const float4* e4 = (const float4*)(cb + (size_t)kk[c] * D);
        float d0 = 0.f, d1 = 0.f, d2 = 0.f, d3 = 0.f;
#pragma unroll
        for (int i = 0; i < 16; ++i) {
          float4 v = e4[i];
          float4 zv = zp[i];
          d0 = fmaf(zv.x, v.x, d0);
          d1 = fmaf(zv.y, v.y, d1);
          d2 = fmaf(zv.z, v.z, d2);
          d3 = fmaf(zv.w, v.w, d3);
        }
        float dot = (d0 + d1) + (d2 + d3);
        dx[c] = (rzx + scbn[kk[c]]) - 2.0f * dot;
      }
      if ((dx[1] < dx[0]) || (dx[1] == dx[0] && bk2 < bk1)) bk1 = bk2;
    }
    skf[row] = bk1;
    out_idx[rowbase + row] = (float)bk1;
    atomicAdd(&lhist[bk1], 1u);
  }
  __syncthreads();

  // ---- flush per-block histogram: one global atomic per distinct code
#pragma unroll
  for (int j = 0; j < KC / 256; ++j) {
    unsigned int c = lhist[tid + 256 * j];
    if (c) atomicAdd(&hist[tid + 256 * j], c);
  }

  // ---- epilogue: quantized write (exact fp32 codebook rows) + loss partial
  float lsum = 0.f;
#pragma unroll
  for (int it = 0; it < 4; ++it) {
    int f4 = it * 256 + tid;
    int r = f4 >> 4;
    int c4 = (f4 & 15) * 4;
    int bk = skf[r];
    const float4 q = *(const float4*)(cb + (size_t)bk * D + c4);
    const int grow = rowbase + r;
    const float4 zv = *(const float4*)(z + (size_t)grow * D + c4);
    *(float4*)(out_q + (size_t)grow * D + c4) = q;
    float ax = q.x - zv.x, ay = q.y - zv.y, az = q.z - zv.z, aw = q.w - zv.w;
    lsum += ax * ax + ay * ay + az * az + aw * aw;
  }
#pragma unroll
  for (int off = 32; off > 0; off >>= 1) lsum += __shfl_down(lsum, off, 64);
  if (lane == 0) swav[wav] = lsum;
  __syncthreads();
  if (tid == 0) {
    atomicAdd(loss_acc, (swav[0] + swav[1]) + (swav[2] + swav[3]));
  }
}

__global__ __launch_bounds__(1024) void vq_final(
    const unsigned int* __restrict__ hist, const float* __restrict__ loss_acc,
    float* __restrict__ out_loss, float* __restrict__ out_perp, float inv_n,
    float inv_nd) {
  __shared__ float part[16];
  const int t = threadIdx.x;
  const int lane = t & 63;
  const int wav = t >> 6;
  float p = (float)hist[t] * inv_n;
  float v = p * logf(p + 1e-10f);
#pragma unroll
  for (int off = 32; off > 0; off >>= 1) v += __shfl_down(v, off, 64);
  if (lane == 0) part[wav] = v;
  __syncthreads();
  if (t == 0) {
    float s = 0.f;
#pragma unroll
    for (int j = 0; j < 16; ++j) s += part[j];
    *out_perp = expf(-s);
    // q_latent + 0.25*e_latent, both numerically mean((q-z)^2)
    *out_loss = 1.25f * loss_acc[0] * inv_nd;
  }
}

extern "C" void kernel_launch(void* const* d_in, const int* in_sizes, int n_in,
                              void* d_out, int out_size, void* d_ws,
                              size_t ws_size, hipStream_t stream) {
  (void)n_in;
  (void)out_size;
  (void)ws_size;
  const float* z = (const float*)d_in[0];
  const float* cb = (const float*)d_in[1];
  const int N = in_sizes[0] / D;  // 32768

  // Output layout (flat float32, reference return order):
  float* out_q = (float*)d_out;                     // N*D
  float* out_loss = (float*)d_out + (size_t)N * D;  // 1
  float* out_idx = out_loss + 1;                    // N
  float* out_perp = out_idx + N;                    // 1

  // Workspace (floats): hist[1024] @0, loss_acc @1024, cbn[1024] @1040,
  // bsplit (short[1024*128]) @ float-idx 2064 (byte 8256, 16B-aligned).
  unsigned int* hist = (unsigned int*)d_ws;
  float* loss_acc = (float*)d_ws + 1024;
  float* cbn = (float*)d_ws + 1040;
  unsigned short* bsplit = (unsigned short*)((float*)d_ws + 2064);

  vq_prep<<<dim3(KC / 256), dim3(256), 0, stream>>>(cb, bsplit, cbn, hist,
                                                    loss_acc);
  vq_main<<<dim3(N / ROWS), dim3(256), 0, stream>>>(z, bsplit, cbn, cb, out_q,
                                                    out_idx, hist, loss_acc);
  vq_final<<<dim3(1), dim3(1024), 0, stream>>>(
      hist, loss_acc, out_loss, out_perp, 1.0f / (float)N,
      1.0f / ((float)N * (float)D));
}